// Round 1
// baseline (555.336 us; speedup 1.0000x reference)
//
#include <hip/hip_runtime.h>
#include <cstdint>
#include <cstddef>

// Problem constants
#define BSZ   32
#define ENCN  512            // tokens per batch
#define SEQL  1024           // d_model
#define NHEAD 8
#define HDIM  128
#define MROWS (BSZ*ENCN)     // 16384 total rows
#define N1    (3*SEQL)       // 3072 qkv features
#define K1    SEQL           // 1024
#define N2    SEQL           // 1024
#define K2    (2*SEQL)       // 2048

typedef __bf16 bf16;
typedef __bf16 bf16x8 __attribute__((ext_vector_type(8)));
typedef __bf16 bf16x4 __attribute__((ext_vector_type(4)));
typedef float  f32x4  __attribute__((ext_vector_type(4)));

__device__ __forceinline__ void gl_lds16(const void* g, void* l) {
  // global -> LDS async copy, 16B per lane. LDS dest = wave-uniform base + lane*16.
  __builtin_amdgcn_global_load_lds(
      (const __attribute__((address_space(1))) void*)(uintptr_t)g,
      (__attribute__((address_space(3))) void*)(uintptr_t)(uint32_t)(uintptr_t)l,
      16, 0, 0);
}

__device__ __forceinline__ f32x4 mfma16(bf16x8 a, bf16x8 b, f32x4 c) {
  return __builtin_amdgcn_mfma_f32_16x16x32_bf16(a, b, c, 0, 0, 0);
}

// ---------------- weight conversion f32 -> bf16 ----------------
__global__ __launch_bounds__(256) void cvt_w_kernel(const float* __restrict__ w_in,
                                                    const float* __restrict__ w_out,
                                                    bf16* __restrict__ wi,
                                                    bf16* __restrict__ wo) {
  int idx = blockIdx.x * 256 + threadIdx.x;   // each converts 4 floats
  int i4  = idx * 4;
  const int NWIN = N1 * K1;                   // 3145728
  if (i4 < NWIN) {
    float4 v = ((const float4*)w_in)[idx];
    bf16x4 o = { (bf16)v.x, (bf16)v.y, (bf16)v.z, (bf16)v.w };
    ((bf16x4*)wi)[idx] = o;
  } else {
    int j = i4 - NWIN;                        // < N2*K2 by grid construction
    float4 v = ((const float4*)w_out)[j >> 2];
    bf16x4 o = { (bf16)v.x, (bf16)v.y, (bf16)v.z, (bf16)v.w };
    ((bf16x4*)wo)[j >> 2] = o;
  }
}

// ---------------- LayerNorm -> bf16 ----------------
__global__ __launch_bounds__(256) void ln_kernel(const float* __restrict__ x,
                                                 const float* __restrict__ g,
                                                 const float* __restrict__ bt,
                                                 bf16* __restrict__ xn) {
  int row = blockIdx.x;
  int t = threadIdx.x;
  const float4 v = ((const float4*)(x + (size_t)row * SEQL))[t];
  float s  = v.x + v.y + v.z + v.w;
  float ss = v.x*v.x + v.y*v.y + v.z*v.z + v.w*v.w;
  for (int off = 32; off; off >>= 1) {
    s  += __shfl_down(s,  off, 64);
    ss += __shfl_down(ss, off, 64);
  }
  __shared__ float red[8];
  int w = t >> 6, l = t & 63;
  if (l == 0) { red[w] = s; red[w + 4] = ss; }
  __syncthreads();
  float st  = red[0] + red[1] + red[2] + red[3];
  float sst = red[4] + red[5] + red[6] + red[7];
  float mu   = st * (1.0f / SEQL);
  float var  = sst * (1.0f / SEQL) - mu * mu;
  float rstd = rsqrtf(var + 1e-5f);
  float4 gv = ((const float4*)g)[t];
  float4 bv = ((const float4*)bt)[t];
  bf16x4 o;
  o[0] = (bf16)((v.x - mu) * rstd * gv.x + bv.x);
  o[1] = (bf16)((v.y - mu) * rstd * gv.y + bv.y);
  o[2] = (bf16)((v.z - mu) * rstd * gv.z + bv.z);
  o[3] = (bf16)((v.w - mu) * rstd * gv.w + bv.w);
  ((bf16x4*)(xn + (size_t)row * SEQL))[t] = o;
}

// ---------------- m97-style bt-GEMM: C[M,N] = A[M,K] @ Bw[N,K]^T + bias (+resid) --------
// MODE 0: out bf16 (qkv). MODE 1: out f32 = acc + bias + resid (final output).
template <int MODE>
__global__ __launch_bounds__(256) void gemm_bt(const bf16* __restrict__ A,
                                               const bf16* __restrict__ Bw,
                                               const float* __restrict__ bias,
                                               const float* __restrict__ resid,
                                               void* __restrict__ Cout,
                                               int M, int N, int K) {
  __shared__ bf16 Als[128 * 32];
  __shared__ bf16 Bls[128 * 32];
  const int tid = threadIdx.x;
  const int w = tid >> 6, l = tid & 63;
  const int wm = w & 1, wn = w >> 1;
  const int q = l >> 4, li = l & 15;
  const int m0 = blockIdx.x * 128;
  const int n0 = blockIdx.y * 128;

  f32x4 acc[4][4] = {};

  for (int k0 = 0; k0 < K; k0 += 32) {
    // stage 128x32 bf16 tiles (8KB each): 2 issues of 4KB per tile.
    {
      int o0 = w * 1024 + l * 16;            // bytes into tile, issue 0
      int o1 = o0 + 4096;                    // issue 1
      int r0 = o0 >> 6, c0 = (o0 & 63) >> 1; // row, col-elem
      int r1 = o1 >> 6, c1 = (o1 & 63) >> 1;
      gl_lds16(A  + (size_t)(m0 + r0) * K + k0 + c0, (char*)Als + w * 1024);
      gl_lds16(A  + (size_t)(m0 + r1) * K + k0 + c1, (char*)Als + 4096 + w * 1024);
      gl_lds16(Bw + (size_t)(n0 + r0) * K + k0 + c0, (char*)Bls + w * 1024);
      gl_lds16(Bw + (size_t)(n0 + r1) * K + k0 + c1, (char*)Bls + 4096 + w * 1024);
    }
    __syncthreads();
    bf16x8 af[4], bfg[4];
#pragma unroll
    for (int i = 0; i < 4; i++)
      af[i] = *(const bf16x8*)&Als[(wm * 64 + i * 16 + li) * 32 + q * 8];
#pragma unroll
    for (int j = 0; j < 4; j++)
      bfg[j] = *(const bf16x8*)&Bls[(wn * 64 + j * 16 + li) * 32 + q * 8];
#pragma unroll
    for (int i = 0; i < 4; i++)
#pragma unroll
      for (int j = 0; j < 4; j++)
        acc[i][j] = mfma16(af[i], bfg[j], acc[i][j]);
    __syncthreads();
  }

#pragma unroll
  for (int i = 0; i < 4; i++)
#pragma unroll
    for (int j = 0; j < 4; j++) {
      int col = n0 + wn * 64 + j * 16 + li;
      float bv = bias[col];
#pragma unroll
      for (int r = 0; r < 4; r++) {
        int row = m0 + wm * 64 + i * 16 + q * 4 + r;
        float v = acc[i][j][r] + bv;
        if (MODE == 0) {
          ((bf16*)Cout)[(size_t)row * N + col] = (bf16)v;
        } else {
          v += resid[(size_t)row * N + col];
          ((float*)Cout)[(size_t)row * N + col] = v;
        }
      }
    }
}

// ---------------- mlp1 on q and k: A1[b, c] = relu(chunk@W1a^T + b1a) . w1b + b1b ------
// chunks: [B*4096, 128] bf16, chunk (b,c) at qkv[b*512 + c/8][tensor*1024 + (c%8)*128]
__global__ __launch_bounds__(256) void mlp1_kernel(const bf16* __restrict__ qkv,
                                                   const float* __restrict__ w1a,
                                                   const float* __restrict__ b1a,
                                                   const float* __restrict__ w1b,
                                                   const float* __restrict__ b1b,
                                                   float* __restrict__ A1q,
                                                   float* __restrict__ A1k) {
  const int bid = blockIdx.x;
  const int tensor = bid >> 10;         // 0=q, 1=k
  const int mtile = bid & 1023;         // 1024 tiles of 128 chunks
  const int tid = threadIdx.x;
  const int w = tid >> 6, l = tid & 63;
  const int wm = w & 1, wn = w >> 1;
  const int q = l >> 4, li = l & 15;

  // preload W1a fragments into registers (B operand: B[k][n] = w1a[n][k])
  bf16x8 bfrag[4][4];
#pragma unroll
  for (int kq = 0; kq < 4; kq++)
#pragma unroll
    for (int j = 0; j < 4; j++) {
      int n = wn * 64 + j * 16 + li;
      const float* wr = w1a + n * 128 + kq * 32 + q * 8;
      bf16x8 t;
#pragma unroll
      for (int e = 0; e < 8; e++) t[e] = (bf16)wr[e];
      bfrag[kq][j] = t;
    }

  f32x4 acc[4][4] = {};
#pragma unroll
  for (int kq = 0; kq < 4; kq++) {
#pragma unroll
    for (int i = 0; i < 4; i++) {
      int cg = mtile * 128 + wm * 64 + i * 16 + li;  // global chunk id
      int b = cg >> 12;
      int c = cg & 4095;
      const bf16* ap = qkv + (size_t)(b * 512 + (c >> 3)) * N1
                           + tensor * 1024 + (c & 7) * 128 + kq * 32 + q * 8;
      bf16x8 af = *(const bf16x8*)ap;
#pragma unroll
      for (int j = 0; j < 4; j++)
        acc[i][j] = mfma16(af, bfrag[kq][j], acc[i][j]);
    }
  }

  float b1av[4], w1bv[4];
#pragma unroll
  for (int j = 0; j < 4; j++) {
    int col = wn * 64 + j * 16 + li;
    b1av[j] = b1a[col];
    w1bv[j] = w1b[col];
  }
  __shared__ float red[2][128];
  float p[4][4];
#pragma unroll
  for (int i = 0; i < 4; i++)
#pragma unroll
    for (int r = 0; r < 4; r++) {
      float s = 0.f;
#pragma unroll
      for (int j = 0; j < 4; j++) {
        float h = acc[i][j][r] + b1av[j];
        s += fmaxf(h, 0.f) * w1bv[j];
      }
      for (int off = 1; off < 16; off <<= 1) s += __shfl_xor(s, off, 64);
      p[i][r] = s;
    }
  if (li == 0) {
#pragma unroll
    for (int i = 0; i < 4; i++)
#pragma unroll
      for (int r = 0; r < 4; r++)
        red[wn][wm * 64 + i * 16 + q * 4 + r] = p[i][r];
  }
  __syncthreads();
  if (tid < 128) {
    float v = red[0][tid] + red[1][tid] + b1b[0];
    float* outp = tensor ? A1k : A1q;
    outp[mtile * 128 + tid] = v;
  }
}

// ---------------- mlp2 on q and k: A2[b, h*128+d] = relu(sum_n t[b,h,n,d]*w2[n] + b2) --
__global__ __launch_bounds__(256) void mlp2_kernel(const bf16* __restrict__ qkv,
                                                   const float* __restrict__ w2,
                                                   const float* __restrict__ b2,
                                                   float* __restrict__ A2q,
                                                   float* __restrict__ A2k) {
  const int bid = blockIdx.x;          // 512 blocks: tensor x (b,h)
  const int tensor = bid >> 8;
  const int bh = bid & 255;
  const int b = bh >> 3, h = bh & 7;
  const int t = threadIdx.x;
  const int d = t & 127, nh = t >> 7;
  float acc = 0.f;
  for (int n = nh; n < 512; n += 2) {
    int row = b * 512 + h * 64 + (n >> 3);
    int col = tensor * 1024 + (n & 7) * 128 + d;
    acc += (float)qkv[(size_t)row * N1 + col] * w2[n];
  }
  __shared__ float red[256];
  red[t] = acc;
  __syncthreads();
  if (t < 128) {
    float s = red[t] + red[t + 128] + b2[0];
    float* o = tensor ? A2k : A2q;
    o[b * 1024 + h * 128 + t] = fmaxf(s, 0.f);
  }
}

// ---------------- scale & concat: Y[row, 0:1024]=v1, Y[row, 1024:2048]=v2 (bf16) -------
__global__ __launch_bounds__(256) void scale_kernel(const bf16* __restrict__ qkv,
                                                    const float* __restrict__ A1q,
                                                    const float* __restrict__ A1k,
                                                    const float* __restrict__ A2q,
                                                    const float* __restrict__ A2k,
                                                    bf16* __restrict__ Y) {
  size_t idx = ((size_t)blockIdx.x * 256 + threadIdx.x) * 8;  // over B*524288 elems
  int b = (int)(idx >> 19);
  int f = (int)(idx & 524287);
  int chunk = f >> 7;
  float a1q = A1q[b * 4096 + chunk];
  float a1k = A1k[b * 4096 + chunk];
  int a2i = b * 1024 + ((f >> 16) << 7) + (f & 127);
  float4 k0 = *(const float4*)&A2k[a2i];
  float4 k1 = *(const float4*)&A2k[a2i + 4];
  float4 q0 = *(const float4*)&A2q[a2i];
  float4 q1 = *(const float4*)&A2q[a2i + 4];
  int row = b * 512 + (f >> 10);
  int col = f & 1023;
  bf16x8 v = *(const bf16x8*)&qkv[(size_t)row * N1 + 2048 + col];
  const float sc = 1.0f / 256.0f;
  float kk[8] = { k0.x, k0.y, k0.z, k0.w, k1.x, k1.y, k1.z, k1.w };
  float qq[8] = { q0.x, q0.y, q0.z, q0.w, q1.x, q1.y, q1.z, q1.w };
  bf16x8 y1, y2;
#pragma unroll
  for (int e = 0; e < 8; e++) {
    float vv = (float)v[e];
    y1[e] = (bf16)(a1q * kk[e] * sc * vv);
    y2[e] = (bf16)(a1k * qq[e] * sc * vv);
  }
  bf16* yr = Y + (size_t)row * K2;
  *(bf16x8*)&yr[col] = y1;
  *(bf16x8*)&yr[1024 + col] = y2;
}

extern "C" void kernel_launch(void* const* d_in, const int* in_sizes, int n_in,
                              void* d_out, int out_size, void* d_ws, size_t ws_size,
                              hipStream_t stream) {
  const float* x     = (const float*)d_in[0];
  const float* ln_g  = (const float*)d_in[1];
  const float* ln_b  = (const float*)d_in[2];
  const float* w_in  = (const float*)d_in[3];
  const float* b_in  = (const float*)d_in[4];
  const float* w1a   = (const float*)d_in[5];
  const float* b1a   = (const float*)d_in[6];
  const float* w1b   = (const float*)d_in[7];
  const float* b1b   = (const float*)d_in[8];
  const float* w2    = (const float*)d_in[9];
  const float* b2    = (const float*)d_in[10];
  const float* w_out = (const float*)d_in[11];
  const float* b_out = (const float*)d_in[12];
  float* out = (float*)d_out;
  char* ws = (char*)d_ws;

  // workspace layout (bytes)
  bf16*  xn   = (bf16*)(ws);                       //  33,554,432
  bf16*  qkv  = (bf16*)(ws + 33554432);            // 100,663,296
  bf16*  Y    = (bf16*)(ws + 134217728);           //  67,108,864
  bf16*  wi_b = (bf16*)(ws + 201326592);           //   6,291,456
  bf16*  wo_b = (bf16*)(ws + 207618048);           //   4,194,304
  float* A1q  = (float*)(ws + 211812352);          //     524,288
  float* A1k  = (float*)(ws + 212336640);          //     524,288
  float* A2q  = (float*)(ws + 212860928);          //     131,072
  float* A2k  = (float*)(ws + 212992000);          //     131,072

  cvt_w_kernel<<<5120, 256, 0, stream>>>(w_in, w_out, wi_b, wo_b);
  ln_kernel<<<MROWS, 256, 0, stream>>>(x, ln_g, ln_b, xn);
  gemm_bt<0><<<dim3(MROWS / 128, N1 / 128), 256, 0, stream>>>(
      xn, wi_b, b_in, nullptr, qkv, MROWS, N1, K1);
  mlp1_kernel<<<2048, 256, 0, stream>>>(qkv, w1a, b1a, w1b, b1b, A1q, A1k);
  mlp2_kernel<<<512, 256, 0, stream>>>(qkv, w2, b2, A2q, A2k);
  scale_kernel<<<8192, 256, 0, stream>>>(qkv, A1q, A1k, A2q, A2k, Y);
  gemm_bt<1><<<dim3(MROWS / 128, N2 / 128), 256, 0, stream>>>(
      Y, wo_b, b_out, x, out, MROWS, N2, K2);
}

// Round 2
// 445.043 us; speedup vs baseline: 1.2478x; 1.2478x over previous
//
#include <hip/hip_runtime.h>
#include <cstdint>
#include <cstddef>

// Problem constants
#define BSZ   32
#define ENCN  512            // tokens per batch
#define SEQL  1024           // d_model
#define NHEAD 8
#define HDIM  128
#define MROWS (BSZ*ENCN)     // 16384 total rows
#define N1    (3*SEQL)       // 3072 qkv features
#define K1    SEQL           // 1024
#define N2    SEQL           // 1024
#define K2    (2*SEQL)       // 2048

typedef __bf16 bf16;
typedef __bf16 bf16x8 __attribute__((ext_vector_type(8)));
typedef __bf16 bf16x4 __attribute__((ext_vector_type(4)));
typedef float  f32x4  __attribute__((ext_vector_type(4)));

__device__ __forceinline__ void gl_lds16(const void* g, void* l) {
  // global -> LDS async copy, 16B per lane. LDS dest = wave-uniform base + lane*16.
  __builtin_amdgcn_global_load_lds(
      (const __attribute__((address_space(1))) void*)(uintptr_t)g,
      (__attribute__((address_space(3))) void*)(uintptr_t)(uint32_t)(uintptr_t)l,
      16, 0, 0);
}

__device__ __forceinline__ f32x4 mfma16(bf16x8 a, bf16x8 b, f32x4 c) {
  return __builtin_amdgcn_mfma_f32_16x16x32_bf16(a, b, c, 0, 0, 0);
}

// ---------------- weight conversion f32 -> bf16 (w_in, w_out, w_m1a) ----------------
__global__ __launch_bounds__(256) void cvt_w_kernel(const float* __restrict__ w_in,
                                                    const float* __restrict__ w_out,
                                                    const float* __restrict__ w1a,
                                                    bf16* __restrict__ wi,
                                                    bf16* __restrict__ wo,
                                                    bf16* __restrict__ w1ab) {
  int idx = blockIdx.x * 256 + threadIdx.x;   // float4 index
  const int NWIN4 = (N1 * K1) / 4;            // 786432
  const int NOUT4 = (N2 * K2) / 4;            // 524288
  const float4* src;
  bf16x4* dst;
  int j;
  if (idx < NWIN4) {
    src = (const float4*)w_in;  dst = (bf16x4*)wi;  j = idx;
  } else if (idx < NWIN4 + NOUT4) {
    src = (const float4*)w_out; dst = (bf16x4*)wo;  j = idx - NWIN4;
  } else {
    src = (const float4*)w1a;   dst = (bf16x4*)w1ab; j = idx - NWIN4 - NOUT4;
  }
  float4 v = src[j];
  bf16x4 o = { (bf16)v.x, (bf16)v.y, (bf16)v.z, (bf16)v.w };
  dst[j] = o;
}

// ---------------- LayerNorm -> bf16 ----------------
__global__ __launch_bounds__(256) void ln_kernel(const float* __restrict__ x,
                                                 const float* __restrict__ g,
                                                 const float* __restrict__ bt,
                                                 bf16* __restrict__ xn) {
  int row = blockIdx.x;
  int t = threadIdx.x;
  const float4 v = ((const float4*)(x + (size_t)row * SEQL))[t];
  float s  = v.x + v.y + v.z + v.w;
  float ss = v.x*v.x + v.y*v.y + v.z*v.z + v.w*v.w;
  for (int off = 32; off; off >>= 1) {
    s  += __shfl_down(s,  off, 64);
    ss += __shfl_down(ss, off, 64);
  }
  __shared__ float red[8];
  int w = t >> 6, l = t & 63;
  if (l == 0) { red[w] = s; red[w + 4] = ss; }
  __syncthreads();
  float st  = red[0] + red[1] + red[2] + red[3];
  float sst = red[4] + red[5] + red[6] + red[7];
  float mu   = st * (1.0f / SEQL);
  float var  = sst * (1.0f / SEQL) - mu * mu;
  float rstd = rsqrtf(var + 1e-5f);
  float4 gv = ((const float4*)g)[t];
  float4 bv = ((const float4*)bt)[t];
  bf16x4 o;
  o[0] = (bf16)((v.x - mu) * rstd * gv.x + bv.x);
  o[1] = (bf16)((v.y - mu) * rstd * gv.y + bv.y);
  o[2] = (bf16)((v.z - mu) * rstd * gv.z + bv.z);
  o[3] = (bf16)((v.w - mu) * rstd * gv.w + bv.w);
  ((bf16x4*)(xn + (size_t)row * SEQL))[t] = o;
}

// ---------------- qkv GEMM: 128x128 tile, BK=32, XOR-swizzled LDS --------------------
// C[M,N] = A[M,K] @ Bw[N,K]^T + bias, out bf16.
__global__ __launch_bounds__(256) void gemm_bt(const bf16* __restrict__ A,
                                               const bf16* __restrict__ Bw,
                                               const float* __restrict__ bias,
                                               bf16* __restrict__ Cout,
                                               int M, int N, int K) {
  __shared__ bf16 Als[128 * 32];
  __shared__ bf16 Bls[128 * 32];
  const int tid = threadIdx.x;
  const int w = tid >> 6, l = tid & 63;
  const int wm = w & 1, wn = w >> 1;
  const int q = l >> 4, li = l & 15;
  const int m0 = blockIdx.x * 128;
  const int n0 = blockIdx.y * 128;

  // staging source mapping with XOR swizzle: LDS slot (r, c=tid&3) holds
  // global 16B chunk (r, (tid&3) ^ (r&3)).
  const int sr = tid >> 2;                       // 0..63 (issue 0 rows)
  const int sc = ((tid & 3) ^ (sr & 3)) * 8;     // element col of 16B chunk

  f32x4 acc[4][4] = {};

  for (int k0 = 0; k0 < K; k0 += 32) {
    gl_lds16(A  + (size_t)(m0 + sr)      * K + k0 + sc, (char*)Als + w * 1024);
    gl_lds16(A  + (size_t)(m0 + 64 + sr) * K + k0 + sc, (char*)Als + 4096 + w * 1024);
    gl_lds16(Bw + (size_t)(n0 + sr)      * K + k0 + sc, (char*)Bls + w * 1024);
    gl_lds16(Bw + (size_t)(n0 + 64 + sr) * K + k0 + sc, (char*)Bls + 4096 + w * 1024);
    __syncthreads();
    bf16x8 af[4], bfg[4];
    const int cx = (q ^ (li & 3)) << 3;          // swizzled chunk offset (elements)
#pragma unroll
    for (int i = 0; i < 4; i++)
      af[i] = *(const bf16x8*)&Als[(wm * 64 + i * 16 + li) * 32 + cx];
#pragma unroll
    for (int j = 0; j < 4; j++)
      bfg[j] = *(const bf16x8*)&Bls[(wn * 64 + j * 16 + li) * 32 + cx];
#pragma unroll
    for (int i = 0; i < 4; i++)
#pragma unroll
      for (int j = 0; j < 4; j++)
        acc[i][j] = mfma16(af[i], bfg[j], acc[i][j]);
    __syncthreads();
  }

#pragma unroll
  for (int i = 0; i < 4; i++)
#pragma unroll
    for (int j = 0; j < 4; j++) {
      int col = n0 + wn * 64 + j * 16 + li;
      float bv = bias[col];
#pragma unroll
      for (int r = 0; r < 4; r++) {
        int row = m0 + wm * 64 + i * 16 + q * 4 + r;
        Cout[(size_t)row * N + col] = (bf16)(acc[i][j][r] + bv);
      }
    }
}

// ---------------- output GEMM: 256x128 tile, 512 threads, BK=32, swizzled ------------
// out = A[M,K] @ Bw[N,K]^T + bias + resid (f32 out).
__global__ __launch_bounds__(512) void gemm_wide(const bf16* __restrict__ A,
                                                 const bf16* __restrict__ Bw,
                                                 const float* __restrict__ bias,
                                                 const float* __restrict__ resid,
                                                 float* __restrict__ Cout,
                                                 int M, int N, int K) {
  __shared__ bf16 Als[256 * 32];   // 16 KB
  __shared__ bf16 Bls[128 * 32];   //  8 KB
  const int tid = threadIdx.x;
  const int w = tid >> 6, l = tid & 63;
  const int wm = w & 3, wn = w >> 2;        // 4 m-quadrants x 2 n-halves
  const int q = l >> 4, li = l & 15;
  const int m0 = blockIdx.x * 256;
  const int n0 = blockIdx.y * 128;

  const int sr = tid >> 2;                  // 0..127
  const int sc = ((tid & 3) ^ (sr & 3)) * 8;

  f32x4 acc[4][4] = {};

  for (int k0 = 0; k0 < K; k0 += 32) {
    gl_lds16(A  + (size_t)(m0 + sr)       * K + k0 + sc, (char*)Als + w * 1024);
    gl_lds16(A  + (size_t)(m0 + 128 + sr) * K + k0 + sc, (char*)Als + 8192 + w * 1024);
    gl_lds16(Bw + (size_t)(n0 + sr)       * K + k0 + sc, (char*)Bls + w * 1024);
    __syncthreads();
    bf16x8 af[4], bfg[4];
    const int cx = (q ^ (li & 3)) << 3;
#pragma unroll
    for (int i = 0; i < 4; i++)
      af[i] = *(const bf16x8*)&Als[(wm * 64 + i * 16 + li) * 32 + cx];
#pragma unroll
    for (int j = 0; j < 4; j++)
      bfg[j] = *(const bf16x8*)&Bls[(wn * 64 + j * 16 + li) * 32 + cx];
#pragma unroll
    for (int i = 0; i < 4; i++)
#pragma unroll
      for (int j = 0; j < 4; j++)
        acc[i][j] = mfma16(af[i], bfg[j], acc[i][j]);
    __syncthreads();
  }

#pragma unroll
  for (int i = 0; i < 4; i++)
#pragma unroll
    for (int j = 0; j < 4; j++) {
      int col = n0 + wn * 64 + j * 16 + li;
      float bv = bias[col];
#pragma unroll
      for (int r = 0; r < 4; r++) {
        int row = m0 + wm * 64 + i * 16 + q * 4 + r;
        Cout[(size_t)row * N + col] =
            acc[i][j][r] + bv + resid[(size_t)row * N + col];
      }
    }
}

// ---------------- mlp1 on q and k: A1[b, c] = relu(chunk@W1a^T + b1a) . w1b + b1b ------
// chunks: [B*4096, 128] bf16, chunk (b,c) at qkv[b*512 + c/8][tensor*1024 + (c%8)*128]
__global__ __launch_bounds__(256) void mlp1_kernel(const bf16* __restrict__ qkv,
                                                   const bf16* __restrict__ w1ab,
                                                   const float* __restrict__ b1a,
                                                   const float* __restrict__ w1b,
                                                   const float* __restrict__ b1b,
                                                   float* __restrict__ A1q,
                                                   float* __restrict__ A1k) {
  const int bid = blockIdx.x;
  const int tensor = bid >> 10;         // 0=q, 1=k
  const int mtile = bid & 1023;         // 1024 tiles of 128 chunks
  const int tid = threadIdx.x;
  const int w = tid >> 6, l = tid & 63;
  const int wm = w & 1, wn = w >> 1;
  const int q = l >> 4, li = l & 15;

  // preload W1a fragments (B operand: B[k][n] = w1a[n][k]) via bf16x8 vector loads
  bf16x8 bfrag[4][4];
#pragma unroll
  for (int kq = 0; kq < 4; kq++)
#pragma unroll
    for (int j = 0; j < 4; j++) {
      int n = wn * 64 + j * 16 + li;
      bfrag[kq][j] = *(const bf16x8*)&w1ab[n * 128 + kq * 32 + q * 8];
    }

  f32x4 acc[4][4] = {};
#pragma unroll
  for (int kq = 0; kq < 4; kq++) {
#pragma unroll
    for (int i = 0; i < 4; i++) {
      int cg = mtile * 128 + wm * 64 + i * 16 + li;  // global chunk id
      int b = cg >> 12;
      int c = cg & 4095;
      const bf16* ap = qkv + (size_t)(b * 512 + (c >> 3)) * N1
                           + tensor * 1024 + (c & 7) * 128 + kq * 32 + q * 8;
      bf16x8 af = *(const bf16x8*)ap;
#pragma unroll
      for (int j = 0; j < 4; j++)
        acc[i][j] = mfma16(af, bfrag[kq][j], acc[i][j]);
    }
  }

  float b1av[4], w1bv[4];
#pragma unroll
  for (int j = 0; j < 4; j++) {
    int col = wn * 64 + j * 16 + li;
    b1av[j] = b1a[col];
    w1bv[j] = w1b[col];
  }
  __shared__ float red[2][128];
  float p[4][4];
#pragma unroll
  for (int i = 0; i < 4; i++)
#pragma unroll
    for (int r = 0; r < 4; r++) {
      float s = 0.f;
#pragma unroll
      for (int j = 0; j < 4; j++) {
        float h = acc[i][j][r] + b1av[j];
        s += fmaxf(h, 0.f) * w1bv[j];
      }
      for (int off = 1; off < 16; off <<= 1) s += __shfl_xor(s, off, 64);
      p[i][r] = s;
    }
  if (li == 0) {
#pragma unroll
    for (int i = 0; i < 4; i++)
#pragma unroll
      for (int r = 0; r < 4; r++)
        red[wn][wm * 64 + i * 16 + q * 4 + r] = p[i][r];
  }
  __syncthreads();
  if (tid < 128) {
    float v = red[0][tid] + red[1][tid] + b1b[0];
    float* outp = tensor ? A1k : A1q;
    outp[mtile * 128 + tid] = v;
  }
}

// ---------------- mlp2: A2[b, h*128+d] = relu(sum_n t[b,h,n,d]*w2[n] + b2) ------------
// coalesced bf16x8 loads; block = (tensor, b, h); 64 rows x 1024 cols per block.
__global__ __launch_bounds__(256) void mlp2_kernel(const bf16* __restrict__ qkv,
                                                   const float* __restrict__ w2,
                                                   const float* __restrict__ b2,
                                                   float* __restrict__ A2q,
                                                   float* __restrict__ A2k) {
  __shared__ float w2s[512];
  __shared__ float red[256][8];
  const int bid = blockIdx.x;          // 512 blocks
  const int tensor = bid >> 8;
  const int bh = bid & 255;
  const int b = bh >> 3, h = bh & 7;
  const int t = threadIdx.x;
  w2s[t] = w2[t];
  w2s[t + 256] = w2[t + 256];
  __syncthreads();

  const int half = t >> 7, cg = t & 127;   // col-group of 8
  const bf16* base = qkv + (size_t)(b * 512 + h * 64) * N1 + tensor * 1024 + cg * 8;
  float acc[8] = {0, 0, 0, 0, 0, 0, 0, 0};
  for (int rr = half; rr < 64; rr += 2) {
    bf16x8 v = *(const bf16x8*)(base + (size_t)rr * N1);
    float wn = w2s[rr * 8 + (cg >> 4)];  // n = rr*8 + col/128
#pragma unroll
    for (int e = 0; e < 8; e++) acc[e] += (float)v[e] * wn;
  }
#pragma unroll
  for (int e = 0; e < 8; e++) red[t][e] = acc[e];
  __syncthreads();
  if (t < 128) {
    int m = t >> 3, e = t & 7;           // d = m*8 + e = t
    float s = 0.f;
#pragma unroll
    for (int a = 0; a < 8; a++)
      s += red[a * 16 + m][e] + red[128 + a * 16 + m][e];
    s += b2[0];
    float* o = tensor ? A2k : A2q;
    o[b * 1024 + h * 128 + t] = fmaxf(s, 0.f);
  }
}

// ---------------- scale & concat: Y[row, 0:1024]=v1, Y[row, 1024:2048]=v2 (bf16) -------
__global__ __launch_bounds__(256) void scale_kernel(const bf16* __restrict__ qkv,
                                                    const float* __restrict__ A1q,
                                                    const float* __restrict__ A1k,
                                                    const float* __restrict__ A2q,
                                                    const float* __restrict__ A2k,
                                                    bf16* __restrict__ Y) {
  size_t idx = ((size_t)blockIdx.x * 256 + threadIdx.x) * 8;  // over B*524288 elems
  int b = (int)(idx >> 19);
  int f = (int)(idx & 524287);
  int chunk = f >> 7;
  float a1q = A1q[b * 4096 + chunk];
  float a1k = A1k[b * 4096 + chunk];
  int a2i = b * 1024 + ((f >> 16) << 7) + (f & 127);
  float4 k0 = *(const float4*)&A2k[a2i];
  float4 k1 = *(const float4*)&A2k[a2i + 4];
  float4 q0 = *(const float4*)&A2q[a2i];
  float4 q1 = *(const float4*)&A2q[a2i + 4];
  int row = b * 512 + (f >> 10);
  int col = f & 1023;
  bf16x8 v = *(const bf16x8*)&qkv[(size_t)row * N1 + 2048 + col];
  const float sc = 1.0f / 256.0f;
  float kk[8] = { k0.x, k0.y, k0.z, k0.w, k1.x, k1.y, k1.z, k1.w };
  float qq[8] = { q0.x, q0.y, q0.z, q0.w, q1.x, q1.y, q1.z, q1.w };
  bf16x8 y1, y2;
#pragma unroll
  for (int e = 0; e < 8; e++) {
    float vv = (float)v[e];
    y1[e] = (bf16)(a1q * kk[e] * sc * vv);
    y2[e] = (bf16)(a1k * qq[e] * sc * vv);
  }
  bf16* yr = Y + (size_t)row * K2;
  *(bf16x8*)&yr[col] = y1;
  *(bf16x8*)&yr[1024 + col] = y2;
}

extern "C" void kernel_launch(void* const* d_in, const int* in_sizes, int n_in,
                              void* d_out, int out_size, void* d_ws, size_t ws_size,
                              hipStream_t stream) {
  const float* x     = (const float*)d_in[0];
  const float* ln_g  = (const float*)d_in[1];
  const float* ln_b  = (const float*)d_in[2];
  const float* w_in  = (const float*)d_in[3];
  const float* b_in  = (const float*)d_in[4];
  const float* w1a   = (const float*)d_in[5];
  const float* b1a   = (const float*)d_in[6];
  const float* w1b   = (const float*)d_in[7];
  const float* b1b   = (const float*)d_in[8];
  const float* w2    = (const float*)d_in[9];
  const float* b2    = (const float*)d_in[10];
  const float* w_out = (const float*)d_in[11];
  const float* b_out = (const float*)d_in[12];
  float* out = (float*)d_out;
  char* ws = (char*)d_ws;

  // workspace layout (bytes)
  bf16*  xn   = (bf16*)(ws);                       //  33,554,432
  bf16*  qkv  = (bf16*)(ws + 33554432);            // 100,663,296
  bf16*  Y    = (bf16*)(ws + 134217728);           //  67,108,864
  bf16*  wi_b = (bf16*)(ws + 201326592);           //   6,291,456
  bf16*  wo_b = (bf16*)(ws + 207618048);           //   4,194,304
  float* A1q  = (float*)(ws + 211812352);          //     524,288
  float* A1k  = (float*)(ws + 212336640);          //     524,288
  float* A2q  = (float*)(ws + 212860928);          //     131,072
  float* A2k  = (float*)(ws + 212992000);          //     131,072
  bf16*  w1ab = (bf16*)(ws + 213123072);           //      32,768

  cvt_w_kernel<<<5136, 256, 0, stream>>>(w_in, w_out, w1a, wi_b, wo_b, w1ab);
  ln_kernel<<<MROWS, 256, 0, stream>>>(x, ln_g, ln_b, xn);
  gemm_bt<<<dim3(MROWS / 128, N1 / 128), 256, 0, stream>>>(
      xn, wi_b, b_in, qkv, MROWS, N1, K1);
  mlp1_kernel<<<2048, 256, 0, stream>>>(qkv, w1ab, b1a, w1b, b1b, A1q, A1k);
  mlp2_kernel<<<512, 256, 0, stream>>>(qkv, w2, b2, A2q, A2k);
  scale_kernel<<<8192, 256, 0, stream>>>(qkv, A1q, A1k, A2q, A2k, Y);
  gemm_wide<<<dim3(MROWS / 256, N2 / 128), 512, 0, stream>>>(
      Y, wo_b, b_out, x, out, MROWS, N2, K2);
}

// Round 3
// 320.305 us; speedup vs baseline: 1.7338x; 1.3894x over previous
//
#include <hip/hip_runtime.h>
#include <cstdint>
#include <cstddef>

// Problem constants
#define BSZ   32
#define ENCN  512            // tokens per batch
#define SEQL  1024           // d_model
#define MROWS (BSZ*ENCN)     // 16384 total rows
#define N1    (3*SEQL)       // 3072 qkv features
#define K1    SEQL           // 1024
#define N2    SEQL           // 1024
#define K2    (2*SEQL)       // 2048

typedef __bf16 bf16;
typedef __bf16 bf16x8 __attribute__((ext_vector_type(8)));
typedef __bf16 bf16x4 __attribute__((ext_vector_type(4)));
typedef float  f32x4  __attribute__((ext_vector_type(4)));
typedef int    i32x4  __attribute__((ext_vector_type(4)));
typedef int    i32x8  __attribute__((ext_vector_type(8)));

__device__ __forceinline__ void gl_lds16(const void* g, void* l) {
  // global -> LDS async copy, 16B per lane. LDS dest = wave-uniform base + lane*16.
  __builtin_amdgcn_global_load_lds(
      (const __attribute__((address_space(1))) void*)(uintptr_t)g,
      (__attribute__((address_space(3))) void*)(uintptr_t)(uint32_t)(uintptr_t)l,
      16, 0, 0);
}

__device__ __forceinline__ f32x4 mfma16(bf16x8 a, bf16x8 b, f32x4 c) {
  return __builtin_amdgcn_mfma_f32_16x16x32_bf16(a, b, c, 0, 0, 0);
}

// pack 4 floats -> 4 fp8 e4m3 bytes (OCP on gfx950), little-endian
__device__ __forceinline__ uint32_t pk4_fp8(float a, float b, float c, float d) {
  int v = __builtin_amdgcn_cvt_pk_fp8_f32(a, b, 0, false);   // bytes 0,1
  v = __builtin_amdgcn_cvt_pk_fp8_f32(c, d, v, true);        // bytes 2,3
  return (uint32_t)v;
}

// ---------------- weight conversion: w_in,w_out -> fp8(x64); w1a -> bf16 ----------------
__global__ __launch_bounds__(256) void cvt_w_kernel(const float* __restrict__ w_in,
                                                    const float* __restrict__ w_out,
                                                    const float* __restrict__ w1a,
                                                    uint8_t* __restrict__ wi8,
                                                    uint8_t* __restrict__ wo8,
                                                    bf16* __restrict__ w1ab) {
  int idx = blockIdx.x * 256 + threadIdx.x;   // float4 index
  const int NWIN4 = (N1 * K1) / 4;            // 786432
  const int NOUT4 = (N2 * K2) / 4;            // 524288
  if (idx < NWIN4) {
    float4 v = ((const float4*)w_in)[idx];
    ((uint32_t*)wi8)[idx] = pk4_fp8(v.x * 64.f, v.y * 64.f, v.z * 64.f, v.w * 64.f);
  } else if (idx < NWIN4 + NOUT4) {
    int j = idx - NWIN4;
    float4 v = ((const float4*)w_out)[j];
    ((uint32_t*)wo8)[j] = pk4_fp8(v.x * 64.f, v.y * 64.f, v.z * 64.f, v.w * 64.f);
  } else {
    int j = idx - NWIN4 - NOUT4;              // < 4096
    float4 v = ((const float4*)w1a)[j];
    bf16x4 o = { (bf16)v.x, (bf16)v.y, (bf16)v.z, (bf16)v.w };
    ((bf16x4*)w1ab)[j] = o;
  }
}

// ---------------- LayerNorm -> fp8 e4m3 (unit scale) ----------------
__global__ __launch_bounds__(256) void ln_kernel(const float* __restrict__ x,
                                                 const float* __restrict__ g,
                                                 const float* __restrict__ bt,
                                                 uint8_t* __restrict__ xn8) {
  int row = blockIdx.x;
  int t = threadIdx.x;
  const float4 v = ((const float4*)(x + (size_t)row * SEQL))[t];
  float s  = v.x + v.y + v.z + v.w;
  float ss = v.x*v.x + v.y*v.y + v.z*v.z + v.w*v.w;
  for (int off = 32; off; off >>= 1) {
    s  += __shfl_down(s,  off, 64);
    ss += __shfl_down(ss, off, 64);
  }
  __shared__ float red[8];
  int w = t >> 6, l = t & 63;
  if (l == 0) { red[w] = s; red[w + 4] = ss; }
  __syncthreads();
  float st  = red[0] + red[1] + red[2] + red[3];
  float sst = red[4] + red[5] + red[6] + red[7];
  float mu   = st * (1.0f / SEQL);
  float var  = sst * (1.0f / SEQL) - mu * mu;
  float rstd = rsqrtf(var + 1e-5f);
  float4 gv = ((const float4*)g)[t];
  float4 bv = ((const float4*)bt)[t];
  float y0 = (v.x - mu) * rstd * gv.x + bv.x;
  float y1 = (v.y - mu) * rstd * gv.y + bv.y;
  float y2 = (v.z - mu) * rstd * gv.z + bv.z;
  float y3 = (v.w - mu) * rstd * gv.w + bv.w;
  ((uint32_t*)(xn8 + (size_t)row * SEQL))[t] = pk4_fp8(y0, y1, y2, y3);
}

// ---------------- MX-fp8 GEMM: C[M,N] = (A*2^(SA-127)) @ (Bw*2^(SB-127))^T + bias -------
// A[M,K], Bw[N,K] fp8 e4m3. 128x128 tile, BK=128, 16x16x128 scaled MFMA.
// LDS swizzle: slot (row, c) holds global 16B chunk (row, c ^ (row&7)).
// MODE 0: out bf16. MODE 1: out f32 = acc + bias + resid.
template <int MODE, int SA, int SB>
__global__ __launch_bounds__(256) void gemm_fp8(const uint8_t* __restrict__ A,
                                                const uint8_t* __restrict__ Bw,
                                                const float* __restrict__ bias,
                                                const float* __restrict__ resid,
                                                void* __restrict__ Cout,
                                                int M, int N, int K) {
  __shared__ uint8_t Als[128 * 128];   // 16 KB
  __shared__ uint8_t Bls[128 * 128];   // 16 KB
  const int tid = threadIdx.x;
  const int w = tid >> 6, l = tid & 63;
  const int wm = w & 1, wn = w >> 1;
  const int q = l >> 4, li = l & 15;
  const int m0 = blockIdx.x * 128;
  const int n0 = blockIdx.y * 128;

  // staging: thread t writes LDS bytes [is*4096 + t*16 .. +16); row = is*32 + (t>>3),
  // slot = t&7 -> fetch global chunk (row, (t&7) ^ ((t>>3)&7)).
  const int srow = tid >> 3;                          // 0..31 within issue
  const int scol = ((tid & 7) ^ (srow & 7)) << 4;     // source byte col within BK

  // fragment read offsets (swizzled): lane wants global chunks (row, 2q), (row, 2q+1)
  const int c0 = ((2 * q)     ^ (li & 7)) << 4;
  const int c1 = ((2 * q + 1) ^ (li & 7)) << 4;

  f32x4 acc[4][4] = {};

  for (int k0 = 0; k0 < K; k0 += 128) {
#pragma unroll
    for (int is = 0; is < 4; is++) {
      gl_lds16(A  + (size_t)(m0 + is * 32 + srow) * K + k0 + scol,
               (char*)Als + is * 4096 + w * 1024);
      gl_lds16(Bw + (size_t)(n0 + is * 32 + srow) * K + k0 + scol,
               (char*)Bls + is * 4096 + w * 1024);
    }
    __syncthreads();
    i32x8 af[4], bfg[4];
#pragma unroll
    for (int i = 0; i < 4; i++) {
      int r = wm * 64 + i * 16 + li;
      i32x4 lo = *(const i32x4*)&Als[r * 128 + c0];
      i32x4 hi = *(const i32x4*)&Als[r * 128 + c1];
      af[i] = i32x8{lo[0], lo[1], lo[2], lo[3], hi[0], hi[1], hi[2], hi[3]};
    }
#pragma unroll
    for (int j = 0; j < 4; j++) {
      int r = wn * 64 + j * 16 + li;
      i32x4 lo = *(const i32x4*)&Bls[r * 128 + c0];
      i32x4 hi = *(const i32x4*)&Bls[r * 128 + c1];
      bfg[j] = i32x8{lo[0], lo[1], lo[2], lo[3], hi[0], hi[1], hi[2], hi[3]};
    }
#pragma unroll
    for (int i = 0; i < 4; i++)
#pragma unroll
      for (int j = 0; j < 4; j++)
        acc[i][j] = __builtin_amdgcn_mfma_scale_f32_16x16x128_f8f6f4(
            af[i], bfg[j], acc[i][j], 0 /*A fmt fp8*/, 0 /*B fmt fp8*/,
            0, SA, 0, SB);
    __syncthreads();
  }

#pragma unroll
  for (int i = 0; i < 4; i++)
#pragma unroll
    for (int j = 0; j < 4; j++) {
      int col = n0 + wn * 64 + j * 16 + li;
      float bv = bias[col];
#pragma unroll
      for (int r = 0; r < 4; r++) {
        int row = m0 + wm * 64 + i * 16 + q * 4 + r;
        float v = acc[i][j][r] + bv;
        if (MODE == 0) {
          ((bf16*)Cout)[(size_t)row * N + col] = (bf16)v;
        } else {
          ((float*)Cout)[(size_t)row * N + col] = v + resid[(size_t)row * N + col];
        }
      }
    }
}

// ---------------- mlp1 on q and k: A1[b, c] = relu(chunk@W1a^T + b1a) . w1b + b1b ------
// chunks: [B*4096, 128] bf16, chunk (b,c) at qkv[b*512 + c/8][tensor*1024 + (c%8)*128]
__global__ __launch_bounds__(256) void mlp1_kernel(const bf16* __restrict__ qkv,
                                                   const bf16* __restrict__ w1ab,
                                                   const float* __restrict__ b1a,
                                                   const float* __restrict__ w1b,
                                                   const float* __restrict__ b1b,
                                                   float* __restrict__ A1q,
                                                   float* __restrict__ A1k) {
  const int bid = blockIdx.x;
  const int tensor = bid >> 10;         // 0=q, 1=k
  const int mtile = bid & 1023;         // 1024 tiles of 128 chunks
  const int tid = threadIdx.x;
  const int w = tid >> 6, l = tid & 63;
  const int wm = w & 1, wn = w >> 1;
  const int q = l >> 4, li = l & 15;

  bf16x8 bfrag[4][4];
#pragma unroll
  for (int kq = 0; kq < 4; kq++)
#pragma unroll
    for (int j = 0; j < 4; j++) {
      int n = wn * 64 + j * 16 + li;
      bfrag[kq][j] = *(const bf16x8*)&w1ab[n * 128 + kq * 32 + q * 8];
    }

  f32x4 acc[4][4] = {};
#pragma unroll
  for (int kq = 0; kq < 4; kq++) {
#pragma unroll
    for (int i = 0; i < 4; i++) {
      int cg = mtile * 128 + wm * 64 + i * 16 + li;  // global chunk id
      int b = cg >> 12;
      int c = cg & 4095;
      const bf16* ap = qkv + (size_t)(b * 512 + (c >> 3)) * N1
                           + tensor * 1024 + (c & 7) * 128 + kq * 32 + q * 8;
      bf16x8 af = *(const bf16x8*)ap;
#pragma unroll
      for (int j = 0; j < 4; j++)
        acc[i][j] = mfma16(af, bfrag[kq][j], acc[i][j]);
    }
  }

  float b1av[4], w1bv[4];
#pragma unroll
  for (int j = 0; j < 4; j++) {
    int col = wn * 64 + j * 16 + li;
    b1av[j] = b1a[col];
    w1bv[j] = w1b[col];
  }
  __shared__ float red[2][128];
  float p[4][4];
#pragma unroll
  for (int i = 0; i < 4; i++)
#pragma unroll
    for (int r = 0; r < 4; r++) {
      float s = 0.f;
#pragma unroll
      for (int j = 0; j < 4; j++) {
        float h = acc[i][j][r] + b1av[j];
        s += fmaxf(h, 0.f) * w1bv[j];
      }
      for (int off = 1; off < 16; off <<= 1) s += __shfl_xor(s, off, 64);
      p[i][r] = s;
    }
  if (li == 0) {
#pragma unroll
    for (int i = 0; i < 4; i++)
#pragma unroll
      for (int r = 0; r < 4; r++)
        red[wn][wm * 64 + i * 16 + q * 4 + r] = p[i][r];
  }
  __syncthreads();
  if (tid < 128) {
    float v = red[0][tid] + red[1][tid] + b1b[0];
    float* outp = tensor ? A1k : A1q;
    outp[mtile * 128 + tid] = v;
  }
}

// ---------------- mlp2: A2[b, h*128+d] = relu(sum_n t[b,h,n,d]*w2[n] + b2) ------------
__global__ __launch_bounds__(256) void mlp2_kernel(const bf16* __restrict__ qkv,
                                                   const float* __restrict__ w2,
                                                   const float* __restrict__ b2,
                                                   float* __restrict__ A2q,
                                                   float* __restrict__ A2k) {
  __shared__ float w2s[512];
  __shared__ float red[256][8];
  const int bid = blockIdx.x;          // 512 blocks
  const int tensor = bid >> 8;
  const int bh = bid & 255;
  const int b = bh >> 3, h = bh & 7;
  const int t = threadIdx.x;
  w2s[t] = w2[t];
  w2s[t + 256] = w2[t + 256];
  __syncthreads();

  const int half = t >> 7, cg = t & 127;   // col-group of 8
  const bf16* base = qkv + (size_t)(b * 512 + h * 64) * N1 + tensor * 1024 + cg * 8;
  float acc[8] = {0, 0, 0, 0, 0, 0, 0, 0};
  for (int rr = half; rr < 64; rr += 2) {
    bf16x8 v = *(const bf16x8*)(base + (size_t)rr * N1);
    float wn = w2s[rr * 8 + (cg >> 4)];
#pragma unroll
    for (int e = 0; e < 8; e++) acc[e] += (float)v[e] * wn;
  }
#pragma unroll
  for (int e = 0; e < 8; e++) red[t][e] = acc[e];
  __syncthreads();
  if (t < 128) {
    int m = t >> 3, e = t & 7;
    float s = 0.f;
#pragma unroll
    for (int a = 0; a < 8; a++)
      s += red[a * 16 + m][e] + red[128 + a * 16 + m][e];
    s += b2[0];
    float* o = tensor ? A2k : A2q;
    o[b * 1024 + h * 128 + t] = fmaxf(s, 0.f);
  }
}

// ---------------- scale & concat -> fp8 Y (values x 2^14) ----------------
__global__ __launch_bounds__(256) void scale_kernel(const bf16* __restrict__ qkv,
                                                    const float* __restrict__ A1q,
                                                    const float* __restrict__ A1k,
                                                    const float* __restrict__ A2q,
                                                    const float* __restrict__ A2k,
                                                    uint8_t* __restrict__ Y) {
  size_t idx = ((size_t)blockIdx.x * 256 + threadIdx.x) * 8;  // over B*524288 elems
  int b = (int)(idx >> 19);
  int f = (int)(idx & 524287);
  int chunk = f >> 7;
  // combined factor: (1/256 score scale) * 2^14 fp8 pre-scale = 64
  float a1q = A1q[b * 4096 + chunk] * 64.f;
  float a1k = A1k[b * 4096 + chunk] * 64.f;
  int a2i = b * 1024 + ((f >> 16) << 7) + (f & 127);
  float4 k0 = *(const float4*)&A2k[a2i];
  float4 k1 = *(const float4*)&A2k[a2i + 4];
  float4 q0 = *(const float4*)&A2q[a2i];
  float4 q1 = *(const float4*)&A2q[a2i + 4];
  int row = b * 512 + (f >> 10);
  int col = f & 1023;
  bf16x8 v = *(const bf16x8*)&qkv[(size_t)row * N1 + 2048 + col];
  float kk[8] = { k0.x, k0.y, k0.z, k0.w, k1.x, k1.y, k1.z, k1.w };
  float qq[8] = { q0.x, q0.y, q0.z, q0.w, q1.x, q1.y, q1.z, q1.w };
  float y1[8], y2[8];
#pragma unroll
  for (int e = 0; e < 8; e++) {
    float vv = (float)v[e];
    y1[e] = a1q * kk[e] * vv;
    y2[e] = a1k * qq[e] * vv;
  }
  uint8_t* yr = Y + (size_t)row * K2;
  ((uint32_t*)(yr + col))[0] = pk4_fp8(y1[0], y1[1], y1[2], y1[3]);
  ((uint32_t*)(yr + col))[1] = pk4_fp8(y1[4], y1[5], y1[6], y1[7]);
  ((uint32_t*)(yr + 1024 + col))[0] = pk4_fp8(y2[0], y2[1], y2[2], y2[3]);
  ((uint32_t*)(yr + 1024 + col))[1] = pk4_fp8(y2[4], y2[5], y2[6], y2[7]);
}

extern "C" void kernel_launch(void* const* d_in, const int* in_sizes, int n_in,
                              void* d_out, int out_size, void* d_ws, size_t ws_size,
                              hipStream_t stream) {
  const float* x     = (const float*)d_in[0];
  const float* ln_g  = (const float*)d_in[1];
  const float* ln_b  = (const float*)d_in[2];
  const float* w_in  = (const float*)d_in[3];
  const float* b_in  = (const float*)d_in[4];
  const float* w1a   = (const float*)d_in[5];
  const float* b1a   = (const float*)d_in[6];
  const float* w1b   = (const float*)d_in[7];
  const float* b1b   = (const float*)d_in[8];
  const float* w2    = (const float*)d_in[9];
  const float* b2    = (const float*)d_in[10];
  const float* w_out = (const float*)d_in[11];
  const float* b_out = (const float*)d_in[12];
  float* out = (float*)d_out;
  char* ws = (char*)d_ws;

  // workspace layout (bytes)
  uint8_t* xn8  = (uint8_t*)(ws);                   //  16,777,216
  bf16*    qkv  = (bf16*)   (ws + 16777216);        // 100,663,296
  uint8_t* Y8   = (uint8_t*)(ws + 117440512);       //  33,554,432
  uint8_t* wi8  = (uint8_t*)(ws + 150994944);       //   3,145,728
  uint8_t* wo8  = (uint8_t*)(ws + 154140672);       //   2,097,152
  bf16*    w1ab = (bf16*)   (ws + 156237824);       //      32,768
  float*   A1q  = (float*)  (ws + 156270592);       //     524,288
  float*   A1k  = (float*)  (ws + 156794880);       //     524,288
  float*   A2q  = (float*)  (ws + 157319168);       //     131,072
  float*   A2k  = (float*)  (ws + 157450240);       //     131,072

  cvt_w_kernel<<<5136, 256, 0, stream>>>(w_in, w_out, w1a, wi8, wo8, w1ab);
  ln_kernel<<<MROWS, 256, 0, stream>>>(x, ln_g, ln_b, xn8);
  // A unit scale (127), W pre-scaled by 2^6 -> scale byte 121
  gemm_fp8<0, 127, 121><<<dim3(MROWS / 128, N1 / 128), 256, 0, stream>>>(
      xn8, wi8, b_in, nullptr, qkv, MROWS, N1, K1);
  mlp1_kernel<<<2048, 256, 0, stream>>>(qkv, w1ab, b1a, w1b, b1b, A1q, A1k);
  mlp2_kernel<<<512, 256, 0, stream>>>(qkv, w2, b2, A2q, A2k);
  scale_kernel<<<8192, 256, 0, stream>>>(qkv, A1q, A1k, A2q, A2k, Y8);
  // Y pre-scaled by 2^14 -> scale byte 113; W by 2^6 -> 121
  gemm_fp8<1, 113, 121><<<dim3(MROWS / 128, N2 / 128), 256, 0, stream>>>(
      Y8, wo8, b_out, x, out, MROWS, N2, K2);
}

// Round 4
// 319.375 us; speedup vs baseline: 1.7388x; 1.0029x over previous
//
#include <hip/hip_runtime.h>
#include <cstdint>
#include <cstddef>

// Problem constants
#define BSZ   32
#define ENCN  512            // tokens per batch
#define SEQL  1024           // d_model
#define MROWS (BSZ*ENCN)     // 16384 total rows
#define N1    (3*SEQL)       // 3072 qkv features
#define K1    SEQL           // 1024
#define N2    SEQL           // 1024
#define K2    (2*SEQL)       // 2048

typedef __bf16 bf16;
typedef __bf16 bf16x8 __attribute__((ext_vector_type(8)));
typedef __bf16 bf16x4 __attribute__((ext_vector_type(4)));
typedef float  f32x4  __attribute__((ext_vector_type(4)));
typedef int    i32x4  __attribute__((ext_vector_type(4)));
typedef int    i32x8  __attribute__((ext_vector_type(8)));

__device__ __forceinline__ void gl_lds16(const void* g, void* l) {
  // global -> LDS async copy, 16B per lane. LDS dest = wave-uniform base + lane*16.
  __builtin_amdgcn_global_load_lds(
      (const __attribute__((address_space(1))) void*)(uintptr_t)g,
      (__attribute__((address_space(3))) void*)(uintptr_t)(uint32_t)(uintptr_t)l,
      16, 0, 0);
}

__device__ __forceinline__ f32x4 mfma16(bf16x8 a, bf16x8 b, f32x4 c) {
  return __builtin_amdgcn_mfma_f32_16x16x32_bf16(a, b, c, 0, 0, 0);
}

// pack 4 floats -> 4 fp8 e4m3 bytes (OCP on gfx950), little-endian
__device__ __forceinline__ uint32_t pk4_fp8(float a, float b, float c, float d) {
  int v = __builtin_amdgcn_cvt_pk_fp8_f32(a, b, 0, false);   // bytes 0,1
  v = __builtin_amdgcn_cvt_pk_fp8_f32(c, d, v, true);        // bytes 2,3
  return (uint32_t)v;
}

// ---------------- weight conversion: w_in,w_out -> fp8(x64); w1a -> bf16 ----------------
__global__ __launch_bounds__(256) void cvt_w_kernel(const float* __restrict__ w_in,
                                                    const float* __restrict__ w_out,
                                                    const float* __restrict__ w1a,
                                                    uint8_t* __restrict__ wi8,
                                                    uint8_t* __restrict__ wo8,
                                                    bf16* __restrict__ w1ab) {
  int idx = blockIdx.x * 256 + threadIdx.x;   // float4 index
  const int NWIN4 = (N1 * K1) / 4;            // 786432
  const int NOUT4 = (N2 * K2) / 4;            // 524288
  if (idx < NWIN4) {
    float4 v = ((const float4*)w_in)[idx];
    ((uint32_t*)wi8)[idx] = pk4_fp8(v.x * 64.f, v.y * 64.f, v.z * 64.f, v.w * 64.f);
  } else if (idx < NWIN4 + NOUT4) {
    int j = idx - NWIN4;
    float4 v = ((const float4*)w_out)[j];
    ((uint32_t*)wo8)[j] = pk4_fp8(v.x * 64.f, v.y * 64.f, v.z * 64.f, v.w * 64.f);
  } else {
    int j = idx - NWIN4 - NOUT4;              // < 4096
    float4 v = ((const float4*)w1a)[j];
    bf16x4 o = { (bf16)v.x, (bf16)v.y, (bf16)v.z, (bf16)v.w };
    ((bf16x4*)w1ab)[j] = o;
  }
}

// ---------------- LayerNorm -> fp8 e4m3 (unit scale) ----------------
__global__ __launch_bounds__(256) void ln_kernel(const float* __restrict__ x,
                                                 const float* __restrict__ g,
                                                 const float* __restrict__ bt,
                                                 uint8_t* __restrict__ xn8) {
  int row = blockIdx.x;
  int t = threadIdx.x;
  const float4 v = ((const float4*)(x + (size_t)row * SEQL))[t];
  float s  = v.x + v.y + v.z + v.w;
  float ss = v.x*v.x + v.y*v.y + v.z*v.z + v.w*v.w;
  for (int off = 32; off; off >>= 1) {
    s  += __shfl_down(s,  off, 64);
    ss += __shfl_down(ss, off, 64);
  }
  __shared__ float red[8];
  int w = t >> 6, l = t & 63;
  if (l == 0) { red[w] = s; red[w + 4] = ss; }
  __syncthreads();
  float st  = red[0] + red[1] + red[2] + red[3];
  float sst = red[4] + red[5] + red[6] + red[7];
  float mu   = st * (1.0f / SEQL);
  float var  = sst * (1.0f / SEQL) - mu * mu;
  float rstd = rsqrtf(var + 1e-5f);
  float4 gv = ((const float4*)g)[t];
  float4 bv = ((const float4*)bt)[t];
  float y0 = (v.x - mu) * rstd * gv.x + bv.x;
  float y1 = (v.y - mu) * rstd * gv.y + bv.y;
  float y2 = (v.z - mu) * rstd * gv.z + bv.z;
  float y3 = (v.w - mu) * rstd * gv.w + bv.w;
  ((uint32_t*)(xn8 + (size_t)row * SEQL))[t] = pk4_fp8(y0, y1, y2, y3);
}

// ---------------- MX-fp8 GEMM: C[M,N] = (A*2^(SA-127)) @ (Bw*2^(SB-127))^T + bias -------
// A[M,K], Bw[N,K] fp8 e4m3. 128x128 tile, BK=128, 16x16x128 scaled MFMA.
// LDS swizzle: slot (row, c) holds global 16B chunk (row, c ^ (row&7)).
// MODE 0: out bf16. MODE 1: out f32 = acc + bias + resid.
template <int MODE, int SA, int SB>
__global__ __launch_bounds__(256) void gemm_fp8(const uint8_t* __restrict__ A,
                                                const uint8_t* __restrict__ Bw,
                                                const float* __restrict__ bias,
                                                const float* __restrict__ resid,
                                                void* __restrict__ Cout,
                                                int M, int N, int K) {
  __shared__ uint8_t Als[128 * 128];   // 16 KB
  __shared__ uint8_t Bls[128 * 128];   // 16 KB
  const int tid = threadIdx.x;
  const int w = tid >> 6, l = tid & 63;
  const int wm = w & 1, wn = w >> 1;
  const int q = l >> 4, li = l & 15;
  const int m0 = blockIdx.x * 128;
  const int n0 = blockIdx.y * 128;

  // staging: thread t writes LDS bytes [is*4096 + t*16 .. +16); row = is*32 + (t>>3),
  // slot = t&7 -> fetch global chunk (row, (t&7) ^ ((t>>3)&7)).
  const int srow = tid >> 3;                          // 0..31 within issue
  const int scol = ((tid & 7) ^ (srow & 7)) << 4;     // source byte col within BK

  // fragment read offsets (swizzled): lane wants global chunks (row, 2q), (row, 2q+1)
  const int c0 = ((2 * q)     ^ (li & 7)) << 4;
  const int c1 = ((2 * q + 1) ^ (li & 7)) << 4;

  f32x4 acc[4][4] = {};

  for (int k0 = 0; k0 < K; k0 += 128) {
#pragma unroll
    for (int is = 0; is < 4; is++) {
      gl_lds16(A  + (size_t)(m0 + is * 32 + srow) * K + k0 + scol,
               (char*)Als + is * 4096 + w * 1024);
      gl_lds16(Bw + (size_t)(n0 + is * 32 + srow) * K + k0 + scol,
               (char*)Bls + is * 4096 + w * 1024);
    }
    __syncthreads();
    i32x8 af[4], bfg[4];
#pragma unroll
    for (int i = 0; i < 4; i++) {
      int r = wm * 64 + i * 16 + li;
      i32x4 lo = *(const i32x4*)&Als[r * 128 + c0];
      i32x4 hi = *(const i32x4*)&Als[r * 128 + c1];
      af[i] = i32x8{lo[0], lo[1], lo[2], lo[3], hi[0], hi[1], hi[2], hi[3]};
    }
#pragma unroll
    for (int j = 0; j < 4; j++) {
      int r = wn * 64 + j * 16 + li;
      i32x4 lo = *(const i32x4*)&Bls[r * 128 + c0];
      i32x4 hi = *(const i32x4*)&Bls[r * 128 + c1];
      bfg[j] = i32x8{lo[0], lo[1], lo[2], lo[3], hi[0], hi[1], hi[2], hi[3]};
    }
#pragma unroll
    for (int i = 0; i < 4; i++)
#pragma unroll
      for (int j = 0; j < 4; j++)
        acc[i][j] = __builtin_amdgcn_mfma_scale_f32_16x16x128_f8f6f4(
            af[i], bfg[j], acc[i][j], 0 /*A fmt fp8*/, 0 /*B fmt fp8*/,
            0, SA, 0, SB);
    __syncthreads();
  }

#pragma unroll
  for (int i = 0; i < 4; i++)
#pragma unroll
    for (int j = 0; j < 4; j++) {
      int col = n0 + wn * 64 + j * 16 + li;
      float bv = bias[col];
#pragma unroll
      for (int r = 0; r < 4; r++) {
        int row = m0 + wm * 64 + i * 16 + q * 4 + r;
        float v = acc[i][j][r] + bv;
        if (MODE == 0) {
          ((bf16*)Cout)[(size_t)row * N + col] = (bf16)v;
        } else {
          ((float*)Cout)[(size_t)row * N + col] = v + resid[(size_t)row * N + col];
        }
      }
    }
}

// ---------------- fused mlp1 + mlp2 + scale: one block per (b,h) group ----------------
// Block handles 64 qkv rows = 512 chunks per tensor. Computes
//   A1[T][n] = relu(chunk_n @ W1a^T + b1a) . w1b + b1b        (mlp1, MFMA)
//   A2[T][d] = relu(sum_n t[n,d]*w2[n] + b2)                  (mlp2, reduce)
// then packs Y fp8: Y[row, col] = A1q[n]*A2k[d]*v*64, Y[row,1024+col] = A1k[n]*A2q[d]*v*64.
__global__ __launch_bounds__(512) void attn_fused(const bf16* __restrict__ qkv,
                                                  const bf16* __restrict__ w1ab,
                                                  const float* __restrict__ b1a,
                                                  const float* __restrict__ w1b,
                                                  const float* __restrict__ b1b,
                                                  const float* __restrict__ w2,
                                                  const float* __restrict__ b2,
                                                  uint8_t* __restrict__ Y) {
  __shared__ float A1s[2][512];     // mlp1 outputs (q,k)
  __shared__ float A2s[2][128];     // mlp2 outputs (q,k)
  __shared__ float red1[2][256];    // mlp1 cross-wave partials
  __shared__ float redm[512][8];    // mlp2 partials
  __shared__ float w2s[512];
  const int tid = threadIdx.x;
  const int w = tid >> 6, l = tid & 63;
  const int wm = w & 3, wn = w >> 2;           // 4 chunk-subtiles x 2 feature-halves
  const int q = l >> 4, li = l & 15;
  const int R0 = blockIdx.x * 64;              // first qkv row of this (b,h)
  const bf16* qbase = qkv + (size_t)R0 * N1;

  w2s[tid] = w2[tid];

  // W1a fragments in registers: B[k][n] = w1a[n][k]
  bf16x8 bfrag[4][4];
  float b1av[4], w1bv[4];
#pragma unroll
  for (int j = 0; j < 4; j++) {
    int n = wn * 64 + j * 16 + li;
#pragma unroll
    for (int kq = 0; kq < 4; kq++)
      bfrag[kq][j] = *(const bf16x8*)&w1ab[n * 128 + kq * 32 + q * 8];
    b1av[j] = b1a[n];
    w1bv[j] = w1b[n];
  }
  const float b1b0 = b1b[0], b2_0 = b2[0];

  for (int T = 0; T < 2; T++) {
    // ---- mlp1: 2 passes of 256 chunks ----
    for (int p = 0; p < 2; p++) {
      f32x4 acc[4][4] = {};
#pragma unroll
      for (int kq = 0; kq < 4; kq++) {
#pragma unroll
        for (int i = 0; i < 4; i++) {
          int n = p * 256 + wm * 64 + i * 16 + li;   // chunk index 0..511
          bf16x8 af = *(const bf16x8*)(qbase + (size_t)(n >> 3) * N1
                                       + T * 1024 + (n & 7) * 128 + kq * 32 + q * 8);
#pragma unroll
          for (int j = 0; j < 4; j++)
            acc[i][j] = mfma16(af, bfrag[kq][j], acc[i][j]);
        }
      }
#pragma unroll
      for (int i = 0; i < 4; i++)
#pragma unroll
        for (int r = 0; r < 4; r++) {
          float s = 0.f;
#pragma unroll
          for (int j = 0; j < 4; j++)
            s += fmaxf(acc[i][j][r] + b1av[j], 0.f) * w1bv[j];
          for (int off = 1; off < 16; off <<= 1) s += __shfl_xor(s, off, 64);
          if (li == 0) red1[wn][wm * 64 + i * 16 + q * 4 + r] = s;
        }
      __syncthreads();
      if (tid < 256) A1s[T][p * 256 + tid] = red1[0][tid] + red1[1][tid] + b1b0;
      __syncthreads();
    }
    // ---- mlp2 ----
    {
      const int qu = tid >> 7, cg8 = tid & 127;    // col group of 8
      const bf16* base = qbase + T * 1024 + cg8 * 8;
      float a8[8] = {0, 0, 0, 0, 0, 0, 0, 0};
      for (int rr = qu; rr < 64; rr += 4) {
        bf16x8 v = *(const bf16x8*)(base + (size_t)rr * N1);
        float wgt = w2s[rr * 8 + (cg8 >> 4)];
#pragma unroll
        for (int e = 0; e < 8; e++) a8[e] += (float)v[e] * wgt;
      }
#pragma unroll
      for (int e = 0; e < 8; e++) redm[tid][e] = a8[e];
      __syncthreads();
      if (tid < 128) {
        float s = 0.f;
#pragma unroll
        for (int qu2 = 0; qu2 < 4; qu2++)
#pragma unroll
          for (int cb = 0; cb < 8; cb++)
            s += redm[qu2 * 128 + cb * 16 + (tid >> 3)][tid & 7];
        A2s[T][tid] = fmaxf(s + b2_0, 0.f);
      }
      __syncthreads();
    }
  }

  // ---- scale & pack Y fp8 (x2^14; combined with 1/256 score scale -> x64) ----
  for (int it = 0; it < 16; it++) {
    int g = it * 512 + tid;                       // 0..8191 over 64 rows x 128 groups
    int row_l = g >> 7, colg = g & 127, col = colg * 8;
    int n = row_l * 8 + (colg >> 4);              // chunk index of this row/col-block
    bf16x8 v = *(const bf16x8*)(qbase + (size_t)row_l * N1 + 2048 + col);
    float a1q64 = A1s[0][n] * 64.f, a1k64 = A1s[1][n] * 64.f;
    int d0 = col & 127;
    float y1[8], y2[8];
#pragma unroll
    for (int e = 0; e < 8; e++) {
      float vv = (float)v[e];
      y1[e] = a1q64 * A2s[1][d0 + e] * vv;
      y2[e] = a1k64 * A2s[0][d0 + e] * vv;
    }
    uint8_t* yr = Y + (size_t)(R0 + row_l) * K2;
    ((uint32_t*)(yr + col))[0] = pk4_fp8(y1[0], y1[1], y1[2], y1[3]);
    ((uint32_t*)(yr + col))[1] = pk4_fp8(y1[4], y1[5], y1[6], y1[7]);
    ((uint32_t*)(yr + 1024 + col))[0] = pk4_fp8(y2[0], y2[1], y2[2], y2[3]);
    ((uint32_t*)(yr + 1024 + col))[1] = pk4_fp8(y2[4], y2[5], y2[6], y2[7]);
  }
}

extern "C" void kernel_launch(void* const* d_in, const int* in_sizes, int n_in,
                              void* d_out, int out_size, void* d_ws, size_t ws_size,
                              hipStream_t stream) {
  const float* x     = (const float*)d_in[0];
  const float* ln_g  = (const float*)d_in[1];
  const float* ln_b  = (const float*)d_in[2];
  const float* w_in  = (const float*)d_in[3];
  const float* b_in  = (const float*)d_in[4];
  const float* w1a   = (const float*)d_in[5];
  const float* b1a   = (const float*)d_in[6];
  const float* w1b   = (const float*)d_in[7];
  const float* b1b   = (const float*)d_in[8];
  const float* w2    = (const float*)d_in[9];
  const float* b2    = (const float*)d_in[10];
  const float* w_out = (const float*)d_in[11];
  const float* b_out = (const float*)d_in[12];
  float* out = (float*)d_out;
  char* ws = (char*)d_ws;

  // workspace layout (bytes)
  uint8_t* xn8  = (uint8_t*)(ws);                   //  16,777,216
  bf16*    qkv  = (bf16*)   (ws + 16777216);        // 100,663,296
  uint8_t* Y8   = (uint8_t*)(ws + 117440512);       //  33,554,432
  uint8_t* wi8  = (uint8_t*)(ws + 150994944);       //   3,145,728
  uint8_t* wo8  = (uint8_t*)(ws + 154140672);       //   2,097,152
  bf16*    w1ab = (bf16*)   (ws + 156237824);       //      32,768

  cvt_w_kernel<<<5136, 256, 0, stream>>>(w_in, w_out, w1a, wi8, wo8, w1ab);
  ln_kernel<<<MROWS, 256, 0, stream>>>(x, ln_g, ln_b, xn8);
  // A unit scale (127), W pre-scaled by 2^6 -> scale byte 121
  gemm_fp8<0, 127, 121><<<dim3(MROWS / 128, N1 / 128), 256, 0, stream>>>(
      xn8, wi8, b_in, nullptr, qkv, MROWS, N1, K1);
  attn_fused<<<256, 512, 0, stream>>>(qkv, w1ab, b1a, w1b, b1b, w2, b2, Y8);
  // Y pre-scaled by 2^14 -> scale byte 113; W by 2^6 -> 121
  gemm_fp8<1, 113, 121><<<dim3(MROWS / 128, N2 / 128), 256, 0, stream>>>(
      Y8, wo8, b_out, x, out, MROWS, N2, K2);
}